// Round 6
// baseline (86.975 us; speedup 1.0000x reference)
//
#include <hip/hip_runtime.h>
#include <stdint.h>

#define NB   64
#define NPIX 1024
#define DIM  768
#define KTOP 4

// ---------------------------------------------------------------------------
// Lock-free union-find in LDS with path halving. Roots only decrease; final
// root of each component = its min flat index (the min pixel can never be
// re-parented), independent of race interleaving -> deterministic labels.
// ---------------------------------------------------------------------------
__device__ inline int uf_find(volatile int* p, int x) {
    int px = p[x];
    while (px != x) {
        const int g = p[px];
        if (g != px) p[x] = g;   // path halving (benign race)
        x = g;
        px = p[x];
    }
    return x;
}

__device__ inline void uf_union(volatile int* p, int a, int b) {
    while (true) {
        a = uf_find(p, a);
        b = uf_find(p, b);
        if (a == b) return;
        const int hi = a > b ? a : b;
        const int lo = a ^ b ^ hi;
        const int old = atomicCAS((int*)&p[hi], hi, lo);
        if (old == hi) return;
        a = old; b = lo;
    }
}

// ---------------------------------------------------------------------------
// Fused kernel, LDS-minimized (~8.3 KB so streaming blocks keep high
// occupancy; round-5's 17.9 KB capped blocks/CU and collapsed stream BW).
// Phase A (all blocks): 16 rows of sim = z.q/sqrt(D), fp64 accum; sim stored
//   with RELAXED+AGENT atomic stores (write-through, no wbl2).
// Phase B (last-arriving block per batch): RELAXED+AGENT loads (coherent),
//   then the full region pipeline. LDS overlays:
//     bufA: s_par (1024 int)            -> s_ssum (1024 float)
//     bufB: hist (256 int)+mbits(32 u32)-> s_area (1024 int)
//   (labels are 1..1024, arrays indexed [label-1]; label 0 never accumulated)
// ---------------------------------------------------------------------------
__global__ __launch_bounds__(256) void sgatt_fused(const float* __restrict__ z,
                                                   const float* __restrict__ q,
                                                   float* __restrict__ sim,
                                                   int* __restrict__ cnt,
                                                   float* __restrict__ out) {
    const int b    = blockIdx.y;
    const int t    = threadIdx.x;
    const int lane = t & 63;
    const int wid  = t >> 6;

    __shared__ int   s_bufA[NPIX];        // s_par -> s_ssum(float)
    __shared__ int   s_bufB[NPIX];        // hist+mbits -> s_area
    __shared__ float s_wA[4], s_wB[4];
    __shared__ float s_avv[4];
    __shared__ int   s_avi[4];
    __shared__ unsigned long long s_part[4];
    __shared__ unsigned long long s_win;
    __shared__ float s_smin, s_smax;
    __shared__ int   s_thr;
    __shared__ int   s_top[KTOP];
    __shared__ int   s_lastblk;

    // ================= Phase A: sim rows =================
    {
        const float4* qv = reinterpret_cast<const float4*>(q + (size_t)b * DIM);
        const float4 q0 = qv[lane], q1 = qv[lane + 64], q2 = qv[lane + 128];
        const float rt = sqrtf((float)DIM);
#pragma unroll
        for (int r = 0; r < 4; ++r) {
            const int row = blockIdx.x * 16 + wid * 4 + r;
            const float4* zv =
                reinterpret_cast<const float4*>(z + (size_t)(b * NPIX + row) * DIM);
            const float4 z0 = zv[lane], z1 = zv[lane + 64], z2 = zv[lane + 128];
            double acc = (double)z0.x * q0.x + (double)z0.y * q0.y +
                         (double)z0.z * q0.z + (double)z0.w * q0.w;
            acc += (double)z1.x * q1.x + (double)z1.y * q1.y +
                   (double)z1.z * q1.z + (double)z1.w * q1.w;
            acc += (double)z2.x * q2.x + (double)z2.y * q2.y +
                   (double)z2.z * q2.z + (double)z2.w * q2.w;
#pragma unroll
            for (int o = 32; o > 0; o >>= 1) acc += __shfl_xor(acc, o);
            if (lane == 0)
                __hip_atomic_store(&sim[b * NPIX + row], (float)acc / rt,
                                   __ATOMIC_RELAXED, __HIP_MEMORY_SCOPE_AGENT);
        }
    }
    // __syncthreads() drains vmcnt(0): all write-through stores have reached
    // the coherence point before lane 0 increments the arrival counter.
    __syncthreads();
    if (t == 0)
        s_lastblk = (atomicAdd(&cnt[b], 1) == NB - 1) ? 1 : 0;
    __syncthreads();
    if (!s_lastblk) return;

    // ================= Phase B: region pipeline for batch b =================
    // LDS init: hist = bufB[0:256], mbits = bufB[256:288]
    s_bufB[t] = 0;
    if (t < NPIX / 32) s_bufB[256 + t] = 0;
    int* s_hist = s_bufB;
    unsigned int* s_mbits = reinterpret_cast<unsigned int*>(s_bufB + 256);

    // ---- phase 1: device-coherent sim load, wave min/max ----------------
    const float* simb = sim + (size_t)b * NPIX;
    float svj[4];
#pragma unroll
    for (int j = 0; j < 4; ++j)
        svj[j] = __hip_atomic_load(simb + 4*t + j, __ATOMIC_RELAXED,
                                   __HIP_MEMORY_SCOPE_AGENT);
    float mn = fminf(fminf(svj[0], svj[1]), fminf(svj[2], svj[3]));
    float mx = fmaxf(fmaxf(svj[0], svj[1]), fmaxf(svj[2], svj[3]));
#pragma unroll
    for (int o = 32; o > 0; o >>= 1) {
        mn = fminf(mn, __shfl_xor(mn, o));
        mx = fmaxf(mx, __shfl_xor(mx, o));
    }
    if (lane == 0) { s_wA[wid] = mn; s_wB[wid] = mx; }
    __syncthreads();        // also covers hist/mbits zero-init
    if (t == 0) {
        float a = s_wA[0], c = s_wB[0];
        for (int w = 1; w < 4; ++w) { a = fminf(a, s_wA[w]); c = fmaxf(c, s_wB[w]); }
        s_smin = a; s_smax = c;
    }
    __syncthreads();

    // ---- phase 2: sal + u8 (exact fp32, no FMA) + histogram ------------
    const float smin = s_smin;
    const float den0 = __fadd_rn(__fsub_rn(s_smax, smin), 1e-6f);
    float salj[4];
    int u8j[4];
#pragma unroll
    for (int j = 0; j < 4; ++j) {
        salj[j] = __fdiv_rn(__fsub_rn(svj[j], smin), den0);
        int u = (int)floorf(__fmul_rn(salj[j], 255.0f));
        u8j[j] = min(max(u, 0), 255);
        atomicAdd(&s_hist[u8j[j]], 1);
    }
    __syncthreads();

    // ---- phase 3: Otsu. cumsums exact in fp32 (multiples of 2^-10,
    //      numerators < 2^24) -> shuffle-scan order == reference cumsum.
    {
        const float p = __fmul_rn((float)s_hist[t], 1.0f / 1024.0f);
        float w0 = p;
        float mu = __fmul_rn(p, (float)t);
#pragma unroll
        for (int o = 1; o < 64; o <<= 1) {
            const float aw = __shfl_up(w0, o);
            const float am = __shfl_up(mu, o);
            if (lane >= o) { w0 = __fadd_rn(w0, aw); mu = __fadd_rn(mu, am); }
        }
        if (lane == 63) { s_wA[wid] = w0; s_wB[wid] = mu; }
        __syncthreads();
        float mut = 0.0f;
        for (int w = 0; w < 4; ++w) mut = __fadd_rn(mut, s_wB[w]);
        for (int w = 0; w < wid; ++w) {
            w0 = __fadd_rn(w0, s_wA[w]);
            mu = __fadd_rn(mu, s_wB[w]);
        }
        const float num = __fsub_rn(__fmul_rn(mut, w0), mu);
        const float dn  = __fadd_rn(__fmul_rn(w0, __fsub_rn(1.0f, w0)), 1e-12f);
        float v  = __fdiv_rn(__fmul_rn(num, num), dn);
        int   idx = t;
#pragma unroll
        for (int o = 32; o > 0; o >>= 1) {
            const float v2 = __shfl_xor(v, o);
            const int   i2 = __shfl_xor(idx, o);
            if (v2 > v || (v2 == v && i2 < idx)) { v = v2; idx = i2; }
        }
        if (lane == 0) { s_avv[wid] = v; s_avi[wid] = idx; }
    }
    __syncthreads();
    if (t == 0) {
        float bv = s_avv[0]; int bi = s_avi[0];
        for (int w = 1; w < 4; ++w)
            if (s_avv[w] > bv || (s_avv[w] == bv && s_avi[w] < bi)) {
                bv = s_avv[w]; bi = s_avi[w];
            }
        s_thr = bi;
    }
    __syncthreads();
    const int thr = s_thr;

    // ---- phase 4: mask bitmap + union-find init (s_par = bufA) ----------
    int* s_par = s_bufA;
    int mj[4];
#pragma unroll
    for (int j = 0; j < 4; ++j) {
        const int px = 4*t + j;
        mj[j] = (u8j[j] > thr) ? 1 : 0;
        s_par[px] = px;
        if (mj[j]) atomicOr(&s_mbits[px >> 5], 1u << (px & 31));
    }
    __syncthreads();

    // ---- phase 5: one-pass CC via union-find ----------------------------
#pragma unroll
    for (int j = 0; j < 4; ++j) {
        if (!mj[j]) continue;
        const int px = 4*t + j;
        const int r = px >> 5, c = px & 31;
#define ONMASK(p) ((s_mbits[(p) >> 5] >> ((p) & 31)) & 1u)
        if (c > 0 && ONMASK(px - 1))  uf_union(s_par, px, px - 1);
        if (r > 0) {
            if (c > 0 && ONMASK(px - 33)) uf_union(s_par, px, px - 33);
            if (ONMASK(px - 32))          uf_union(s_par, px, px - 32);
            if (c < 31 && ONMASK(px - 31)) uf_union(s_par, px, px - 31);
        }
#undef ONMASK
    }
    __syncthreads();

    // ---- phase 6: resolve labels, then overlay area/ssum ----------------
    int labj[4];
#pragma unroll
    for (int j = 0; j < 4; ++j) {
        const int px = 4*t + j;
        labj[j] = mj[j] ? (uf_find(s_par, px) + 1) : 0;
    }
    __syncthreads();   // everyone done with s_par (bufA) & mbits (bufB)

    float* s_ssum = reinterpret_cast<float*>(s_bufA);  // [label-1], 1..1024
    int*   s_area = s_bufB;                            // [label-1]
#pragma unroll
    for (int j = 0; j < 4; ++j) { s_area[4*t + j] = 0; s_ssum[4*t + j] = 0.0f; }
    __syncthreads();
#pragma unroll
    for (int j = 0; j < 4; ++j) {
        if (mj[j]) {
            atomicAdd(&s_area[labj[j] - 1], 1);
            atomicAdd(&s_ssum[labj[j] - 1], salj[j]);
        }
    }
    __syncthreads();

    // ---- phase 7: candidate keys + top-4 ---------------------------------
    // valid <=> area >= 20.48 <=> area >= 21; mean > 0 so float bits are
    // order-preserving; ~L in low word => ties pick lower label (lax.top_k).
    unsigned long long key[4];
#pragma unroll
    for (int j = 0; j < 4; ++j) {
        const int L = 4*t + j + 1;
        const int a = s_area[L - 1];
        key[j] = 0ull;
        if (a >= 21) {
            const float mean = __fdiv_rn(s_ssum[L - 1], (float)a);
            key[j] = ((unsigned long long)__float_as_uint(mean) << 32) |
                     (unsigned long long)(0xFFFFFFFFu - (unsigned)L);
        }
    }
    for (int k = 0; k < KTOP; ++k) {
        unsigned long long v =
            max(max(key[0], key[1]), max(key[2], key[3]));
#pragma unroll
        for (int o = 32; o > 0; o >>= 1) {
            const unsigned long long w = __shfl_xor(v, o);
            if (w > v) v = w;
        }
        if (lane == 0) s_part[wid] = v;
        __syncthreads();
        if (t == 0) {
            unsigned long long bb = s_part[0];
            for (int w2 = 1; w2 < 4; ++w2)
                if (s_part[w2] > bb) bb = s_part[w2];
            s_win = bb;
            s_top[k] = (bb != 0ull)
                           ? (int)(0xFFFFFFFFu - (unsigned)(bb & 0xFFFFFFFFull))
                           : -1;
        }
        __syncthreads();
        const unsigned long long win = s_win;
#pragma unroll
        for (int j = 0; j < 4; ++j)
            if (key[j] == win && win != 0ull) key[j] = 0ull;
    }

    // ---- phase 8: write regions + background (float4 stores) -------------
    float* ob = out + (size_t)b * 5 * NPIX;
    int anyr[4] = {0, 0, 0, 0};
#pragma unroll
    for (int k = 0; k < KTOP; ++k) {
        const int tl = s_top[k];
        float4 o;
        float* op = reinterpret_cast<float*>(&o);
#pragma unroll
        for (int j = 0; j < 4; ++j) {
            const int match = (tl >= 0 && labj[j] == tl) ? 1 : 0;
            anyr[j] |= match;
            op[j] = (float)match;
        }
        reinterpret_cast<float4*>(ob + (size_t)k * NPIX)[t] = o;
    }
    {
        float4 o;
        float* op = reinterpret_cast<float*>(&o);
#pragma unroll
        for (int j = 0; j < 4; ++j) op[j] = anyr[j] ? 0.0f : 1.0f;
        reinterpret_cast<float4*>(ob + (size_t)KTOP * NPIX)[t] = o;
    }
}

// ---------------------------------------------------------------------------
extern "C" void kernel_launch(void* const* d_in, const int* in_sizes, int n_in,
                              void* d_out, int out_size, void* d_ws, size_t ws_size,
                              hipStream_t stream) {
    const float* z = (const float*)d_in[0];
    const float* q = (const float*)d_in[1];
    float* out = (float*)d_out;
    float* sim = (float*)d_ws;                                  // 256 KiB
    int*   cnt = (int*)((char*)d_ws + (size_t)NB * NPIX * 4);   // 64 ints

    // cnt must be zero at the start of every call (harness poisons once,
    // never re-poisons between replays); memset node is graph-capturable.
    hipMemsetAsync(cnt, 0, NB * sizeof(int), stream);

    dim3 g(NPIX / 16, NB);
    sgatt_fused<<<g, 256, 0, stream>>>(z, q, sim, cnt, out);
}

// Round 7
// 84.296 us; speedup vs baseline: 1.0318x; 1.0318x over previous
//
#include <hip/hip_runtime.h>
#include <stdint.h>

#define NB   64
#define NPIX 1024
#define DIM  768
#define KTOP 4

// ---------------------------------------------------------------------------
// Lock-free union-find in LDS with path halving. Roots only decrease; final
// root of each component = its min flat index (the min pixel can never be
// re-parented), independent of race interleaving -> deterministic labels.
// ---------------------------------------------------------------------------
__device__ inline int uf_find(volatile int* p, int x) {
    int px = p[x];
    while (px != x) {
        const int g = p[px];
        if (g != px) p[x] = g;   // path halving (benign race)
        x = g;
        px = p[x];
    }
    return x;
}

__device__ inline void uf_union(volatile int* p, int a, int b) {
    while (true) {
        a = uf_find(p, a);
        b = uf_find(p, b);
        if (a == b) return;
        const int hi = a > b ? a : b;
        const int lo = a ^ b ^ hi;
        const int old = atomicCAS((int*)&p[hi], hi, lo);
        if (old == hi) return;
        a = old; b = lo;
    }
}

// ---------------------------------------------------------------------------
// Fused kernel. Phase A restructured for ILP: ALL 15 loads (3 q + 12 z)
// issued before any fp64 math; the 4 relaxed-atomic sim stores moved to the
// very end so they cannot serialize the loads (round-6 regression: atomic
// stores inside the row loop blocked load reordering -> 4 exposed HBM
// round-trips per wave).
// Phase B (last-arriving block per batch) identical to round 6.
// ---------------------------------------------------------------------------
__global__ __launch_bounds__(256) void sgatt_fused(const float* __restrict__ z,
                                                   const float* __restrict__ q,
                                                   float* __restrict__ sim,
                                                   int* __restrict__ cnt,
                                                   float* __restrict__ out) {
    const int b    = blockIdx.y;
    const int t    = threadIdx.x;
    const int lane = t & 63;
    const int wid  = t >> 6;

    __shared__ int   s_bufA[NPIX];        // s_par -> s_ssum(float)
    __shared__ int   s_bufB[NPIX];        // hist+mbits -> s_area
    __shared__ float s_wA[4], s_wB[4];
    __shared__ float s_avv[4];
    __shared__ int   s_avi[4];
    __shared__ unsigned long long s_part[4];
    __shared__ unsigned long long s_win;
    __shared__ float s_smin, s_smax;
    __shared__ int   s_thr;
    __shared__ int   s_top[KTOP];
    __shared__ int   s_lastblk;

    // ================= Phase A: sim rows (loads first, stores last) ======
    {
        const float4* qv = reinterpret_cast<const float4*>(q + (size_t)b * DIM);
        const float4 q0 = qv[lane], q1 = qv[lane + 64], q2 = qv[lane + 128];

        const int row0 = blockIdx.x * 16 + wid * 4;
        const float* zb = z + (size_t)(b * NPIX + row0) * DIM;
        float4 zr0[3], zr1[3], zr2[3], zr3[3];
        {
            const float4* zv0 = reinterpret_cast<const float4*>(zb);
            const float4* zv1 = reinterpret_cast<const float4*>(zb + DIM);
            const float4* zv2 = reinterpret_cast<const float4*>(zb + 2 * DIM);
            const float4* zv3 = reinterpret_cast<const float4*>(zb + 3 * DIM);
            zr0[0] = zv0[lane]; zr0[1] = zv0[lane + 64]; zr0[2] = zv0[lane + 128];
            zr1[0] = zv1[lane]; zr1[1] = zv1[lane + 64]; zr1[2] = zv1[lane + 128];
            zr2[0] = zv2[lane]; zr2[1] = zv2[lane + 64]; zr2[2] = zv2[lane + 128];
            zr3[0] = zv3[lane]; zr3[1] = zv3[lane + 64]; zr3[2] = zv3[lane + 128];
        }

        double acc0, acc1, acc2, acc3;
#define DOT3(acc, zr)                                                         \
        acc = (double)zr[0].x * q0.x + (double)zr[0].y * q0.y +               \
              (double)zr[0].z * q0.z + (double)zr[0].w * q0.w;                \
        acc += (double)zr[1].x * q1.x + (double)zr[1].y * q1.y +              \
               (double)zr[1].z * q1.z + (double)zr[1].w * q1.w;               \
        acc += (double)zr[2].x * q2.x + (double)zr[2].y * q2.y +              \
               (double)zr[2].z * q2.z + (double)zr[2].w * q2.w;
        DOT3(acc0, zr0)
        DOT3(acc1, zr1)
        DOT3(acc2, zr2)
        DOT3(acc3, zr3)
#undef DOT3

#pragma unroll
        for (int o = 32; o > 0; o >>= 1) {
            acc0 += __shfl_xor(acc0, o);
            acc1 += __shfl_xor(acc1, o);
            acc2 += __shfl_xor(acc2, o);
            acc3 += __shfl_xor(acc3, o);
        }
        if (lane == 0) {
            const float rt = sqrtf((float)DIM);
            __hip_atomic_store(&sim[b * NPIX + row0],     (float)acc0 / rt,
                               __ATOMIC_RELAXED, __HIP_MEMORY_SCOPE_AGENT);
            __hip_atomic_store(&sim[b * NPIX + row0 + 1], (float)acc1 / rt,
                               __ATOMIC_RELAXED, __HIP_MEMORY_SCOPE_AGENT);
            __hip_atomic_store(&sim[b * NPIX + row0 + 2], (float)acc2 / rt,
                               __ATOMIC_RELAXED, __HIP_MEMORY_SCOPE_AGENT);
            __hip_atomic_store(&sim[b * NPIX + row0 + 3], (float)acc3 / rt,
                               __ATOMIC_RELAXED, __HIP_MEMORY_SCOPE_AGENT);
        }
    }
    // __syncthreads() drains vmcnt(0): all write-through stores have reached
    // the coherence point before lane 0 increments the arrival counter.
    __syncthreads();
    if (t == 0)
        s_lastblk = (atomicAdd(&cnt[b], 1) == NB - 1) ? 1 : 0;
    __syncthreads();
    if (!s_lastblk) return;

    // ================= Phase B: region pipeline for batch b =================
    // LDS init: hist = bufB[0:256], mbits = bufB[256:288]
    s_bufB[t] = 0;
    if (t < NPIX / 32) s_bufB[256 + t] = 0;
    int* s_hist = s_bufB;
    unsigned int* s_mbits = reinterpret_cast<unsigned int*>(s_bufB + 256);

    // ---- phase 1: device-coherent sim load, wave min/max ----------------
    const float* simb = sim + (size_t)b * NPIX;
    float svj[4];
#pragma unroll
    for (int j = 0; j < 4; ++j)
        svj[j] = __hip_atomic_load(simb + 4*t + j, __ATOMIC_RELAXED,
                                   __HIP_MEMORY_SCOPE_AGENT);
    float mn = fminf(fminf(svj[0], svj[1]), fminf(svj[2], svj[3]));
    float mx = fmaxf(fmaxf(svj[0], svj[1]), fmaxf(svj[2], svj[3]));
#pragma unroll
    for (int o = 32; o > 0; o >>= 1) {
        mn = fminf(mn, __shfl_xor(mn, o));
        mx = fmaxf(mx, __shfl_xor(mx, o));
    }
    if (lane == 0) { s_wA[wid] = mn; s_wB[wid] = mx; }
    __syncthreads();        // also covers hist/mbits zero-init
    if (t == 0) {
        float a = s_wA[0], c = s_wB[0];
        for (int w = 1; w < 4; ++w) { a = fminf(a, s_wA[w]); c = fmaxf(c, s_wB[w]); }
        s_smin = a; s_smax = c;
    }
    __syncthreads();

    // ---- phase 2: sal + u8 (exact fp32, no FMA) + histogram ------------
    const float smin = s_smin;
    const float den0 = __fadd_rn(__fsub_rn(s_smax, smin), 1e-6f);
    float salj[4];
    int u8j[4];
#pragma unroll
    for (int j = 0; j < 4; ++j) {
        salj[j] = __fdiv_rn(__fsub_rn(svj[j], smin), den0);
        int u = (int)floorf(__fmul_rn(salj[j], 255.0f));
        u8j[j] = min(max(u, 0), 255);
        atomicAdd(&s_hist[u8j[j]], 1);
    }
    __syncthreads();

    // ---- phase 3: Otsu. cumsums exact in fp32 (multiples of 2^-10,
    //      numerators < 2^24) -> shuffle-scan order == reference cumsum.
    {
        const float p = __fmul_rn((float)s_hist[t], 1.0f / 1024.0f);
        float w0 = p;
        float mu = __fmul_rn(p, (float)t);
#pragma unroll
        for (int o = 1; o < 64; o <<= 1) {
            const float aw = __shfl_up(w0, o);
            const float am = __shfl_up(mu, o);
            if (lane >= o) { w0 = __fadd_rn(w0, aw); mu = __fadd_rn(mu, am); }
        }
        if (lane == 63) { s_wA[wid] = w0; s_wB[wid] = mu; }
        __syncthreads();
        float mut = 0.0f;
        for (int w = 0; w < 4; ++w) mut = __fadd_rn(mut, s_wB[w]);
        for (int w = 0; w < wid; ++w) {
            w0 = __fadd_rn(w0, s_wA[w]);
            mu = __fadd_rn(mu, s_wB[w]);
        }
        const float num = __fsub_rn(__fmul_rn(mut, w0), mu);
        const float dn  = __fadd_rn(__fmul_rn(w0, __fsub_rn(1.0f, w0)), 1e-12f);
        float v  = __fdiv_rn(__fmul_rn(num, num), dn);
        int   idx = t;
#pragma unroll
        for (int o = 32; o > 0; o >>= 1) {
            const float v2 = __shfl_xor(v, o);
            const int   i2 = __shfl_xor(idx, o);
            if (v2 > v || (v2 == v && i2 < idx)) { v = v2; idx = i2; }
        }
        if (lane == 0) { s_avv[wid] = v; s_avi[wid] = idx; }
    }
    __syncthreads();
    if (t == 0) {
        float bv = s_avv[0]; int bi = s_avi[0];
        for (int w = 1; w < 4; ++w)
            if (s_avv[w] > bv || (s_avv[w] == bv && s_avi[w] < bi)) {
                bv = s_avv[w]; bi = s_avi[w];
            }
        s_thr = bi;
    }
    __syncthreads();
    const int thr = s_thr;

    // ---- phase 4: mask bitmap + union-find init (s_par = bufA) ----------
    int* s_par = s_bufA;
    int mj[4];
#pragma unroll
    for (int j = 0; j < 4; ++j) {
        const int px = 4*t + j;
        mj[j] = (u8j[j] > thr) ? 1 : 0;
        s_par[px] = px;
        if (mj[j]) atomicOr(&s_mbits[px >> 5], 1u << (px & 31));
    }
    __syncthreads();

    // ---- phase 5: one-pass CC via union-find ----------------------------
#pragma unroll
    for (int j = 0; j < 4; ++j) {
        if (!mj[j]) continue;
        const int px = 4*t + j;
        const int r = px >> 5, c = px & 31;
#define ONMASK(p) ((s_mbits[(p) >> 5] >> ((p) & 31)) & 1u)
        if (c > 0 && ONMASK(px - 1))  uf_union(s_par, px, px - 1);
        if (r > 0) {
            if (c > 0 && ONMASK(px - 33)) uf_union(s_par, px, px - 33);
            if (ONMASK(px - 32))          uf_union(s_par, px, px - 32);
            if (c < 31 && ONMASK(px - 31)) uf_union(s_par, px, px - 31);
        }
#undef ONMASK
    }
    __syncthreads();

    // ---- phase 6: resolve labels, then overlay area/ssum ----------------
    int labj[4];
#pragma unroll
    for (int j = 0; j < 4; ++j) {
        const int px = 4*t + j;
        labj[j] = mj[j] ? (uf_find(s_par, px) + 1) : 0;
    }
    __syncthreads();   // everyone done with s_par (bufA) & mbits (bufB)

    float* s_ssum = reinterpret_cast<float*>(s_bufA);  // [label-1], 1..1024
    int*   s_area = s_bufB;                            // [label-1]
#pragma unroll
    for (int j = 0; j < 4; ++j) { s_area[4*t + j] = 0; s_ssum[4*t + j] = 0.0f; }
    __syncthreads();
#pragma unroll
    for (int j = 0; j < 4; ++j) {
        if (mj[j]) {
            atomicAdd(&s_area[labj[j] - 1], 1);
            atomicAdd(&s_ssum[labj[j] - 1], salj[j]);
        }
    }
    __syncthreads();

    // ---- phase 7: candidate keys + top-4 ---------------------------------
    // valid <=> area >= 20.48 <=> area >= 21; mean > 0 so float bits are
    // order-preserving; ~L in low word => ties pick lower label (lax.top_k).
    unsigned long long key[4];
#pragma unroll
    for (int j = 0; j < 4; ++j) {
        const int L = 4*t + j + 1;
        const int a = s_area[L - 1];
        key[j] = 0ull;
        if (a >= 21) {
            const float mean = __fdiv_rn(s_ssum[L - 1], (float)a);
            key[j] = ((unsigned long long)__float_as_uint(mean) << 32) |
                     (unsigned long long)(0xFFFFFFFFu - (unsigned)L);
        }
    }
    for (int k = 0; k < KTOP; ++k) {
        unsigned long long v =
            max(max(key[0], key[1]), max(key[2], key[3]));
#pragma unroll
        for (int o = 32; o > 0; o >>= 1) {
            const unsigned long long w = __shfl_xor(v, o);
            if (w > v) v = w;
        }
        if (lane == 0) s_part[wid] = v;
        __syncthreads();
        if (t == 0) {
            unsigned long long bb = s_part[0];
            for (int w2 = 1; w2 < 4; ++w2)
                if (s_part[w2] > bb) bb = s_part[w2];
            s_win = bb;
            s_top[k] = (bb != 0ull)
                           ? (int)(0xFFFFFFFFu - (unsigned)(bb & 0xFFFFFFFFull))
                           : -1;
        }
        __syncthreads();
        const unsigned long long win = s_win;
#pragma unroll
        for (int j = 0; j < 4; ++j)
            if (key[j] == win && win != 0ull) key[j] = 0ull;
    }

    // ---- phase 8: write regions + background (float4 stores) -------------
    float* ob = out + (size_t)b * 5 * NPIX;
    int anyr[4] = {0, 0, 0, 0};
#pragma unroll
    for (int k = 0; k < KTOP; ++k) {
        const int tl = s_top[k];
        float4 o;
        float* op = reinterpret_cast<float*>(&o);
#pragma unroll
        for (int j = 0; j < 4; ++j) {
            const int match = (tl >= 0 && labj[j] == tl) ? 1 : 0;
            anyr[j] |= match;
            op[j] = (float)match;
        }
        reinterpret_cast<float4*>(ob + (size_t)k * NPIX)[t] = o;
    }
    {
        float4 o;
        float* op = reinterpret_cast<float*>(&o);
#pragma unroll
        for (int j = 0; j < 4; ++j) op[j] = anyr[j] ? 0.0f : 1.0f;
        reinterpret_cast<float4*>(ob + (size_t)KTOP * NPIX)[t] = o;
    }
}

// ---------------------------------------------------------------------------
extern "C" void kernel_launch(void* const* d_in, const int* in_sizes, int n_in,
                              void* d_out, int out_size, void* d_ws, size_t ws_size,
                              hipStream_t stream) {
    const float* z = (const float*)d_in[0];
    const float* q = (const float*)d_in[1];
    float* out = (float*)d_out;
    float* sim = (float*)d_ws;                                  // 256 KiB
    int*   cnt = (int*)((char*)d_ws + (size_t)NB * NPIX * 4);   // 64 ints

    // cnt must be zero at the start of every call (harness poisons once,
    // never re-poisons between replays); memset node is graph-capturable.
    hipMemsetAsync(cnt, 0, NB * sizeof(int), stream);

    dim3 g(NPIX / 16, NB);
    sgatt_fused<<<g, 256, 0, stream>>>(z, q, sim, cnt, out);
}

// Round 8
// 55.477 us; speedup vs baseline: 1.5678x; 1.5195x over previous
//
#include <hip/hip_runtime.h>
#include <stdint.h>

#define NB   64
#define NPIX 1024
#define DIM  768
#define KTOP 4

// ---------------------------------------------------------------------------
// Kernel 1: sim[b,n] = dot(z[b,n,:], q[b,:]) / sqrt(768)
// One wave per row; lane reads float4 (16B) -> fully coalesced.
// fp64 accumulate, single rounding to fp32. (Round-3 proven: absmax 0.)
// ---------------------------------------------------------------------------
__global__ __launch_bounds__(256) void sgatt_sim(const float* __restrict__ z,
                                                 const float* __restrict__ q,
                                                 float* __restrict__ sim) {
    const int b    = blockIdx.y;
    const int lane = threadIdx.x & 63;
    const int wave = threadIdx.x >> 6;
    const float4* qv = reinterpret_cast<const float4*>(q + (size_t)b * DIM);
    const float4 q0 = qv[lane], q1 = qv[lane + 64], q2 = qv[lane + 128];
    const float rt = sqrtf((float)DIM);
#pragma unroll
    for (int r = 0; r < 4; ++r) {
        const int row = blockIdx.x * 16 + wave * 4 + r;
        const float4* zv =
            reinterpret_cast<const float4*>(z + (size_t)(b * NPIX + row) * DIM);
        const float4 z0 = zv[lane], z1 = zv[lane + 64], z2 = zv[lane + 128];
        double acc = (double)z0.x * q0.x + (double)z0.y * q0.y +
                     (double)z0.z * q0.z + (double)z0.w * q0.w;
        acc += (double)z1.x * q1.x + (double)z1.y * q1.y +
               (double)z1.z * q1.z + (double)z1.w * q1.w;
        acc += (double)z2.x * q2.x + (double)z2.y * q2.y +
               (double)z2.z * q2.z + (double)z2.w * q2.w;
#pragma unroll
        for (int o = 32; o > 0; o >>= 1) acc += __shfl_xor(acc, o);
        if (lane == 0) sim[b * NPIX + row] = (float)acc / rt;
    }
}

// ---------------------------------------------------------------------------
// Lock-free union-find in LDS with path halving. Roots only decrease; final
// root of each component = its min flat index (the min pixel can never be
// re-parented), independent of race interleaving -> deterministic labels.
// ---------------------------------------------------------------------------
__device__ inline int uf_find(volatile int* p, int x) {
    int px = p[x];
    while (px != x) {
        const int g = p[px];
        if (g != px) p[x] = g;   // path halving (benign race)
        x = g;
        px = p[x];
    }
    return x;
}

__device__ inline void uf_union(volatile int* p, int a, int b) {
    while (true) {
        a = uf_find(p, a);
        b = uf_find(p, b);
        if (a == b) return;
        const int hi = a > b ? a : b;
        const int lo = a ^ b ^ hi;
        const int old = atomicCAS((int*)&p[hi], hi, lo);
        if (old == hi) return;
        a = old; b = lo;
    }
}

// ---------------------------------------------------------------------------
// Kernel 2: 256 threads x 4 px. Normalize -> Otsu (shfl scan) ->
// CC (union-find + path halving) -> top-4 regions + bg.
// Lean LDS (~8.4 KB) via overlays:
//   bufA: s_par (1024 int)             -> s_ssum (1024 float)
//   bufB: hist (256 int)+mbits(32 u32) -> s_area (1024 int)
// ---------------------------------------------------------------------------
__global__ __launch_bounds__(256) void sgatt_region(const float* __restrict__ sim,
                                                    float* __restrict__ out) {
    const int b    = blockIdx.x;
    const int t    = threadIdx.x;
    const int lane = t & 63;
    const int wid  = t >> 6;

    __shared__ int   s_bufA[NPIX];        // s_par -> s_ssum(float)
    __shared__ int   s_bufB[NPIX];        // hist+mbits -> s_area
    __shared__ float s_wA[4], s_wB[4];
    __shared__ float s_avv[4];
    __shared__ int   s_avi[4];
    __shared__ unsigned long long s_part[4];
    __shared__ unsigned long long s_win;
    __shared__ float s_smin, s_smax;
    __shared__ int   s_thr;
    __shared__ int   s_top[KTOP];

    // LDS init: hist = bufB[0:256], mbits = bufB[256:288]
    s_bufB[t] = 0;
    if (t < NPIX / 32) s_bufB[256 + t] = 0;
    int* s_hist = s_bufB;
    unsigned int* s_mbits = reinterpret_cast<unsigned int*>(s_bufB + 256);

    // ---- phase 1: load sim (float4), wave min/max -----------------------
    const float4 sv4 =
        reinterpret_cast<const float4*>(sim + (size_t)b * NPIX)[t];
    const float svj[4] = {sv4.x, sv4.y, sv4.z, sv4.w};
    float mn = fminf(fminf(svj[0], svj[1]), fminf(svj[2], svj[3]));
    float mx = fmaxf(fmaxf(svj[0], svj[1]), fmaxf(svj[2], svj[3]));
#pragma unroll
    for (int o = 32; o > 0; o >>= 1) {
        mn = fminf(mn, __shfl_xor(mn, o));
        mx = fmaxf(mx, __shfl_xor(mx, o));
    }
    if (lane == 0) { s_wA[wid] = mn; s_wB[wid] = mx; }
    __syncthreads();        // also covers hist/mbits zero-init
    if (t == 0) {
        float a = s_wA[0], c = s_wB[0];
        for (int w = 1; w < 4; ++w) { a = fminf(a, s_wA[w]); c = fmaxf(c, s_wB[w]); }
        s_smin = a; s_smax = c;
    }
    __syncthreads();

    // ---- phase 2: sal + u8 (exact fp32, no FMA) + histogram ------------
    const float smin = s_smin;
    const float den0 = __fadd_rn(__fsub_rn(s_smax, smin), 1e-6f);
    float salj[4];
    int u8j[4];
#pragma unroll
    for (int j = 0; j < 4; ++j) {
        salj[j] = __fdiv_rn(__fsub_rn(svj[j], smin), den0);
        int u = (int)floorf(__fmul_rn(salj[j], 255.0f));
        u8j[j] = min(max(u, 0), 255);
        atomicAdd(&s_hist[u8j[j]], 1);
    }
    __syncthreads();

    // ---- phase 3: Otsu. cumsums exact in fp32 (multiples of 2^-10,
    //      numerators < 2^24) -> shuffle-scan order == reference cumsum.
    {
        const float p = __fmul_rn((float)s_hist[t], 1.0f / 1024.0f);
        float w0 = p;
        float mu = __fmul_rn(p, (float)t);
#pragma unroll
        for (int o = 1; o < 64; o <<= 1) {
            const float aw = __shfl_up(w0, o);
            const float am = __shfl_up(mu, o);
            if (lane >= o) { w0 = __fadd_rn(w0, aw); mu = __fadd_rn(mu, am); }
        }
        if (lane == 63) { s_wA[wid] = w0; s_wB[wid] = mu; }
        __syncthreads();
        float mut = 0.0f;
        for (int w = 0; w < 4; ++w) mut = __fadd_rn(mut, s_wB[w]);
        for (int w = 0; w < wid; ++w) {
            w0 = __fadd_rn(w0, s_wA[w]);
            mu = __fadd_rn(mu, s_wB[w]);
        }
        const float num = __fsub_rn(__fmul_rn(mut, w0), mu);
        const float dn  = __fadd_rn(__fmul_rn(w0, __fsub_rn(1.0f, w0)), 1e-12f);
        float v  = __fdiv_rn(__fmul_rn(num, num), dn);
        int   idx = t;
#pragma unroll
        for (int o = 32; o > 0; o >>= 1) {
            const float v2 = __shfl_xor(v, o);
            const int   i2 = __shfl_xor(idx, o);
            if (v2 > v || (v2 == v && i2 < idx)) { v = v2; idx = i2; }
        }
        if (lane == 0) { s_avv[wid] = v; s_avi[wid] = idx; }
    }
    __syncthreads();
    if (t == 0) {
        float bv = s_avv[0]; int bi = s_avi[0];
        for (int w = 1; w < 4; ++w)
            if (s_avv[w] > bv || (s_avv[w] == bv && s_avi[w] < bi)) {
                bv = s_avv[w]; bi = s_avi[w];
            }
        s_thr = bi;
    }
    __syncthreads();
    const int thr = s_thr;

    // ---- phase 4: mask bitmap + union-find init (s_par = bufA) ----------
    int* s_par = s_bufA;
    int mj[4];
#pragma unroll
    for (int j = 0; j < 4; ++j) {
        const int px = 4*t + j;
        mj[j] = (u8j[j] > thr) ? 1 : 0;
        s_par[px] = px;
        if (mj[j]) atomicOr(&s_mbits[px >> 5], 1u << (px & 31));
    }
    __syncthreads();

    // ---- phase 5: one-pass CC via union-find ----------------------------
#pragma unroll
    for (int j = 0; j < 4; ++j) {
        if (!mj[j]) continue;
        const int px = 4*t + j;
        const int r = px >> 5, c = px & 31;
#define ONMASK(p) ((s_mbits[(p) >> 5] >> ((p) & 31)) & 1u)
        if (c > 0 && ONMASK(px - 1))  uf_union(s_par, px, px - 1);
        if (r > 0) {
            if (c > 0 && ONMASK(px - 33)) uf_union(s_par, px, px - 33);
            if (ONMASK(px - 32))          uf_union(s_par, px, px - 32);
            if (c < 31 && ONMASK(px - 31)) uf_union(s_par, px, px - 31);
        }
#undef ONMASK
    }
    __syncthreads();

    // ---- phase 6: resolve labels, then overlay area/ssum ----------------
    int labj[4];
#pragma unroll
    for (int j = 0; j < 4; ++j) {
        const int px = 4*t + j;
        labj[j] = mj[j] ? (uf_find(s_par, px) + 1) : 0;
    }
    __syncthreads();   // everyone done with s_par (bufA) & mbits (bufB)

    float* s_ssum = reinterpret_cast<float*>(s_bufA);  // [label-1], 1..1024
    int*   s_area = s_bufB;                            // [label-1]
#pragma unroll
    for (int j = 0; j < 4; ++j) { s_area[4*t + j] = 0; s_ssum[4*t + j] = 0.0f; }
    __syncthreads();
#pragma unroll
    for (int j = 0; j < 4; ++j) {
        if (mj[j]) {
            atomicAdd(&s_area[labj[j] - 1], 1);
            atomicAdd(&s_ssum[labj[j] - 1], salj[j]);
        }
    }
    __syncthreads();

    // ---- phase 7: candidate keys + top-4 ---------------------------------
    // valid <=> area >= 20.48 <=> area >= 21; mean > 0 so float bits are
    // order-preserving; ~L in low word => ties pick lower label (lax.top_k).
    unsigned long long key[4];
#pragma unroll
    for (int j = 0; j < 4; ++j) {
        const int L = 4*t + j + 1;
        const int a = s_area[L - 1];
        key[j] = 0ull;
        if (a >= 21) {
            const float mean = __fdiv_rn(s_ssum[L - 1], (float)a);
            key[j] = ((unsigned long long)__float_as_uint(mean) << 32) |
                     (unsigned long long)(0xFFFFFFFFu - (unsigned)L);
        }
    }
    for (int k = 0; k < KTOP; ++k) {
        unsigned long long v =
            max(max(key[0], key[1]), max(key[2], key[3]));
#pragma unroll
        for (int o = 32; o > 0; o >>= 1) {
            const unsigned long long w = __shfl_xor(v, o);
            if (w > v) v = w;
        }
        if (lane == 0) s_part[wid] = v;
        __syncthreads();
        if (t == 0) {
            unsigned long long bb = s_part[0];
            for (int w2 = 1; w2 < 4; ++w2)
                if (s_part[w2] > bb) bb = s_part[w2];
            s_win = bb;
            s_top[k] = (bb != 0ull)
                           ? (int)(0xFFFFFFFFu - (unsigned)(bb & 0xFFFFFFFFull))
                           : -1;
        }
        __syncthreads();
        const unsigned long long win = s_win;
#pragma unroll
        for (int j = 0; j < 4; ++j)
            if (key[j] == win && win != 0ull) key[j] = 0ull;
    }

    // ---- phase 8: write regions + background (float4 stores) -------------
    float* ob = out + (size_t)b * 5 * NPIX;
    int anyr[4] = {0, 0, 0, 0};
#pragma unroll
    for (int k = 0; k < KTOP; ++k) {
        const int tl = s_top[k];
        float4 o;
        float* op = reinterpret_cast<float*>(&o);
#pragma unroll
        for (int j = 0; j < 4; ++j) {
            const int match = (tl >= 0 && labj[j] == tl) ? 1 : 0;
            anyr[j] |= match;
            op[j] = (float)match;
        }
        reinterpret_cast<float4*>(ob + (size_t)k * NPIX)[t] = o;
    }
    {
        float4 o;
        float* op = reinterpret_cast<float*>(&o);
#pragma unroll
        for (int j = 0; j < 4; ++j) op[j] = anyr[j] ? 0.0f : 1.0f;
        reinterpret_cast<float4*>(ob + (size_t)KTOP * NPIX)[t] = o;
    }
}

// ---------------------------------------------------------------------------
extern "C" void kernel_launch(void* const* d_in, const int* in_sizes, int n_in,
                              void* d_out, int out_size, void* d_ws, size_t ws_size,
                              hipStream_t stream) {
    const float* z = (const float*)d_in[0];
    const float* q = (const float*)d_in[1];
    float* out = (float*)d_out;
    float* sim = (float*)d_ws;  // NB*NPIX floats = 256 KiB

    dim3 g1(NPIX / 16, NB);
    sgatt_sim<<<g1, 256, 0, stream>>>(z, q, sim);
    sgatt_region<<<NB, 256, 0, stream>>>(sim, out);
}